// Round 1
// baseline (281.861 us; speedup 1.0000x reference)
//
#include <hip/hip_runtime.h>

// Problem constants (match reference)
#define B 512
#define D 512
#define NC 100000
#define ALPHA 0.5f
#define BETA 0.1f
#define MARGIN 50.0f

// ---------------- Kernel A: gather cg = centers[labels], per-row loss partial ----------------
__global__ __launch_bounds__(256) void k_gather_loss(
    const float* __restrict__ centers, const float* __restrict__ features,
    const int* __restrict__ labels, float* __restrict__ cg, float* __restrict__ rowLoss)
{
    int i = blockIdx.x;          // row 0..511
    int t = threadIdx.x;         // 0..255
    int lab = labels[i];
    const float2* crow = (const float2*)(centers + (size_t)lab * D);
    const float2* frow = (const float2*)(features + (size_t)i * D);
    float2 c = crow[t];
    float2 f = frow[t];
    ((float2*)(cg + (size_t)i * D))[t] = c;
    float dx = c.x - f.x, dy = c.y - f.y;
    float sx = fminf(fmaxf(dx * dx, 1e-12f), 1e12f);
    float sy = fminf(fmaxf(dy * dy, 1e-12f), 1e12f);
    float partial = sx + sy;

    __shared__ float red[256];
    red[t] = partial; __syncthreads();
    for (int s = 128; s > 0; s >>= 1) { if (t < s) red[t] += red[t + s]; __syncthreads(); }
    if (t == 0) rowLoss[i] = red[0];
}

// ---------------- Kernel B: pairwise distances dist[i][j] = ||cg_i - cg_j|| ----------------
// 64x64 output tile per block, block 16x16, each thread 4x4 outputs, K staged 16 at a time.
__global__ __launch_bounds__(256) void k_pairdist(
    const float* __restrict__ cg, float* __restrict__ dist)
{
    __shared__ float As[16][65];   // As[kk][row-in-tile]
    __shared__ float Bs[16][65];
    int tx = threadIdx.x, ty = threadIdx.y;
    int tid = ty * 16 + tx;
    int bi = blockIdx.y, bj = blockIdx.x;
    float acc[4][4] = {};
    for (int k0 = 0; k0 < D; k0 += 16) {
        #pragma unroll
        for (int it = 0; it < 4; ++it) {
            int idx = tid + it * 256;          // 0..1023
            int r = idx >> 4, kk = idx & 15;
            As[kk][r] = cg[(size_t)(bi * 64 + r) * D + k0 + kk];
            Bs[kk][r] = cg[(size_t)(bj * 64 + r) * D + k0 + kk];
        }
        __syncthreads();
        #pragma unroll
        for (int kk = 0; kk < 16; ++kk) {
            float a[4], b[4];
            #pragma unroll
            for (int i2 = 0; i2 < 4; ++i2) a[i2] = As[kk][ty * 4 + i2];
            #pragma unroll
            for (int j2 = 0; j2 < 4; ++j2) b[j2] = Bs[kk][tx * 4 + j2];
            #pragma unroll
            for (int i2 = 0; i2 < 4; ++i2)
                #pragma unroll
                for (int j2 = 0; j2 < 4; ++j2) {
                    float df = a[i2] - b[j2];
                    acc[i2][j2] += df * df;
                }
        }
        __syncthreads();
    }
    #pragma unroll
    for (int i2 = 0; i2 < 4; ++i2)
        #pragma unroll
        for (int j2 = 0; j2 < 4; ++j2) {
            int r = bi * 64 + ty * 4 + i2;
            int c = bj * 64 + tx * 4 + j2;
            dist[r * B + c] = sqrtf(acc[i2][j2]);
        }
}

// ---------------- Kernel C: masked softmax per row (reference semantics) ----------------
// dist_arg = -center_dist; min_v = min_j(dist_arg*mask) = -max_j(mask ? d : 0)
// numer = exp(dist_arg - min_v)*mask = mask ? exp(maxd - d) : 0 ;  Z = sum + 1e-6
__global__ __launch_bounds__(256) void k_softmax(
    const float* __restrict__ dist, const int* __restrict__ labels,
    float* __restrict__ W, float* __restrict__ rowS, float* __restrict__ rowCnt)
{
    int i = blockIdx.x, t = threadIdx.x;
    int li = labels[i];
    float d0 = dist[i * B + t];
    float d1 = dist[i * B + t + 256];
    int m0 = (labels[t] != li) && (d0 <= MARGIN);
    int m1 = (labels[t + 256] != li) && (d1 <= MARGIN);

    __shared__ float red[256];
    // max over masked d (0 if none; d >= 0 always)
    red[t] = fmaxf(m0 ? d0 : 0.f, m1 ? d1 : 0.f); __syncthreads();
    for (int s = 128; s > 0; s >>= 1) { if (t < s) red[t] = fmaxf(red[t], red[t + s]); __syncthreads(); }
    float maxd = red[0]; __syncthreads();

    float n0 = m0 ? expf(maxd - d0) : 0.f;
    float n1 = m1 ? expf(maxd - d1) : 0.f;
    red[t] = n0 + n1; __syncthreads();
    for (int s = 128; s > 0; s >>= 1) { if (t < s) red[t] += red[t + s]; __syncthreads(); }
    float Z = red[0] + 1e-6f; __syncthreads();
    float invZ = 1.f / Z;
    W[i * B + t]       = n0 * invZ;
    W[i * B + t + 256] = n1 * invZ;

    // mask count for the global sum(mask) < 1 check
    red[t] = (float)(m0 + m1); __syncthreads();
    for (int s = 128; s > 0; s >>= 1) { if (t < s) red[t] += red[t + s]; __syncthreads(); }
    if (t == 0) {
        rowS[i] = (Z - 1e-6f) * invZ;   // sum_j W_ij
        rowCnt[i] = red[0];
    }
}

// ---------------- Kernel F: finalize loss, global mask flag, last-write-wins winners ----------------
__global__ __launch_bounds__(512) void k_finalize(
    const float* __restrict__ rowLoss, const float* __restrict__ rowCnt,
    const int* __restrict__ labels, float* __restrict__ d_out0,
    float* __restrict__ flag, int* __restrict__ winner)
{
    int t = threadIdx.x; // 0..511
    __shared__ float red[512];
    red[t] = rowLoss[t]; __syncthreads();
    for (int s = 256; s > 0; s >>= 1) { if (t < s) red[t] += red[t + s]; __syncthreads(); }
    if (t == 0) *d_out0 = red[0] * (1.0f / (float)(B * D));
    __syncthreads();
    red[t] = rowCnt[t]; __syncthreads();
    for (int s = 256; s > 0; s >>= 1) { if (t < s) red[t] += red[t + s]; __syncthreads(); }
    if (t == 0) *flag = (red[0] < 1.0f) ? 0.f : 1.f;

    // winner[i] = 1 iff no later row has the same label (numpy scatter: last write wins)
    int li = labels[t];
    int w = 1;
    for (int j = t + 1; j < B; ++j) if (labels[j] == li) w = 0;
    winner[t] = w;
}

// ---------------- Kernel D: delta2 = S_i*cg_i - W·cg, fused epilogue + scatter ----------------
// new_val[i,d] = cg - ALPHA*(cg - feat) - BETA*flag*delta2 = 0.5*(cg+feat) - 0.1*flag*delta2
__global__ __launch_bounds__(256) void k_delta2_scatter(
    const float* __restrict__ W, const float* __restrict__ cg,
    const float* __restrict__ feat, const float* __restrict__ rowS,
    const int* __restrict__ labels, const int* __restrict__ winner,
    const float* __restrict__ flagp, float* __restrict__ outC)
{
    __shared__ float Ws[16][65];   // Ws[jj][i-in-tile]
    __shared__ float Cs[16][65];   // Cs[jj][d-in-tile]
    int tx = threadIdx.x, ty = threadIdx.y;
    int tid = ty * 16 + tx;
    int bi = blockIdx.y, bd = blockIdx.x;
    float acc[4][4] = {};
    for (int j0 = 0; j0 < B; j0 += 16) {
        #pragma unroll
        for (int it = 0; it < 4; ++it) {
            int idx = tid + it * 256;
            int r = idx >> 4, jj = idx & 15;
            Ws[jj][r] = W[(size_t)(bi * 64 + r) * B + j0 + jj];
            int dd = idx & 63, jj2 = idx >> 6;
            Cs[jj2][dd] = cg[(size_t)(j0 + jj2) * D + bd * 64 + dd];
        }
        __syncthreads();
        #pragma unroll
        for (int kk = 0; kk < 16; ++kk) {
            float w[4], c[4];
            #pragma unroll
            for (int i2 = 0; i2 < 4; ++i2) w[i2] = Ws[kk][ty * 4 + i2];
            #pragma unroll
            for (int j2 = 0; j2 < 4; ++j2) c[j2] = Cs[kk][tx * 4 + j2];
            #pragma unroll
            for (int i2 = 0; i2 < 4; ++i2)
                #pragma unroll
                for (int j2 = 0; j2 < 4; ++j2)
                    acc[i2][j2] += w[i2] * c[j2];
        }
        __syncthreads();
    }
    float flag = *flagp;
    #pragma unroll
    for (int i2 = 0; i2 < 4; ++i2) {
        int i = bi * 64 + ty * 4 + i2;
        float s = rowS[i];
        int wn = winner[i];
        size_t orow = (size_t)labels[i] * D;
        #pragma unroll
        for (int j2 = 0; j2 < 4; ++j2) {
            int d = bd * 64 + tx * 4 + j2;
            float c = cg[(size_t)i * D + d];
            float f = feat[(size_t)i * D + d];
            float delta2 = s * c - acc[i2][j2];
            float val = 0.5f * (c + f) - BETA * flag * delta2;
            if (wn) outC[orow + d] = val;
        }
    }
}

extern "C" void kernel_launch(void* const* d_in, const int* in_sizes, int n_in,
                              void* d_out, int out_size, void* d_ws, size_t ws_size,
                              hipStream_t stream)
{
    const float* features = (const float*)d_in[0];
    const int*   labels   = (const int*)d_in[1];
    const float* centers  = (const float*)d_in[2];

    float* out = (float*)d_out;            // out[0] = loss, out[1..] = new_centers
    float* outC = out + 1;

    // workspace layout (bytes)
    char* ws = (char*)d_ws;
    float* cg      = (float*)(ws);                     // 1 MB
    float* dist    = (float*)(ws + 1048576);           // 1 MB
    float* Wm      = (float*)(ws + 2097152);           // 1 MB
    float* rowLoss = (float*)(ws + 3145728);           // 2 KB
    float* rowS    = (float*)(ws + 3147776);           // 2 KB
    float* rowCnt  = (float*)(ws + 3149824);           // 2 KB
    float* flag    = (float*)(ws + 3151872);           // 4 B
    int*   winner  = (int*)  (ws + 3152896);           // 2 KB

    // Bulk copy centers -> new_centers (rows get overwritten by scatter below)
    hipMemcpyAsync(outC, centers, (size_t)NC * D * sizeof(float),
                   hipMemcpyDeviceToDevice, stream);

    k_gather_loss<<<B, 256, 0, stream>>>(centers, features, labels, cg, rowLoss);
    k_pairdist<<<dim3(8, 8), dim3(16, 16), 0, stream>>>(cg, dist);
    k_softmax<<<B, 256, 0, stream>>>(dist, labels, Wm, rowS, rowCnt);
    k_finalize<<<1, 512, 0, stream>>>(rowLoss, rowCnt, labels, out, flag, winner);
    k_delta2_scatter<<<dim3(8, 8), dim3(16, 16), 0, stream>>>(
        Wm, cg, features, rowS, labels, winner, flag, outC);
}

// Round 3
// 213.159 us; speedup vs baseline: 1.3223x; 1.3223x over previous
//
#include <hip/hip_runtime.h>

// Problem constants (match reference)
#define B 512
#define D 512
#define NC 100000
#define ALPHA 0.5f
#define BETA 0.1f
#define MARGIN 50.0f

typedef float f4 __attribute__((ext_vector_type(4)));

// ---------------- Kernel CP: copy centers -> out+1 (dst only 4B-aligned) ----------------
__global__ __launch_bounds__(256) void k_copy(
    const f4* __restrict__ src, float* __restrict__ dstBase, int n4)
{
    int idx = blockIdx.x * blockDim.x + threadIdx.x;
    int stride = gridDim.x * blockDim.x;
    for (int i = idx; i < n4; i += stride) {
        f4 v = __builtin_nontemporal_load(&src[i]);
        float* d = dstBase + 4 * (size_t)i;
        __builtin_nontemporal_store(v.x, d + 0);
        __builtin_nontemporal_store(v.y, d + 1);
        __builtin_nontemporal_store(v.z, d + 2);
        __builtin_nontemporal_store(v.w, d + 3);
    }
}

// ---------------- Kernel A: gather cg = centers[labels], per-row loss partial ----------------
__global__ __launch_bounds__(256) void k_gather_loss(
    const float* __restrict__ centers, const float* __restrict__ features,
    const int* __restrict__ labels, float* __restrict__ cg, float* __restrict__ rowLoss)
{
    int i = blockIdx.x;          // row 0..511
    int t = threadIdx.x;         // 0..255
    int lab = labels[i];
    const float2* crow = (const float2*)(centers + (size_t)lab * D);
    const float2* frow = (const float2*)(features + (size_t)i * D);
    float2 c = crow[t];
    float2 f = frow[t];
    ((float2*)(cg + (size_t)i * D))[t] = c;
    float dx = c.x - f.x, dy = c.y - f.y;
    float sx = fminf(fmaxf(dx * dx, 1e-12f), 1e12f);
    float sy = fminf(fmaxf(dy * dy, 1e-12f), 1e12f);
    float partial = sx + sy;

    __shared__ float red[256];
    red[t] = partial; __syncthreads();
    for (int s = 128; s > 0; s >>= 1) { if (t < s) red[t] += red[t + s]; __syncthreads(); }
    if (t == 0) rowLoss[i] = red[0];
}

// ---------------- Kernel B: pairwise distances dist[i][j] = ||cg_i - cg_j|| ----------------
__global__ __launch_bounds__(256) void k_pairdist(
    const float* __restrict__ cg, float* __restrict__ dist)
{
    __shared__ float As[16][65];   // As[kk][row-in-tile]
    __shared__ float Bs[16][65];
    int tx = threadIdx.x, ty = threadIdx.y;
    int tid = ty * 16 + tx;
    int bi = blockIdx.y, bj = blockIdx.x;
    float acc[4][4] = {};
    for (int k0 = 0; k0 < D; k0 += 16) {
        #pragma unroll
        for (int it = 0; it < 4; ++it) {
            int idx = tid + it * 256;          // 0..1023
            int r = idx >> 4, kk = idx & 15;
            As[kk][r] = cg[(size_t)(bi * 64 + r) * D + k0 + kk];
            Bs[kk][r] = cg[(size_t)(bj * 64 + r) * D + k0 + kk];
        }
        __syncthreads();
        #pragma unroll
        for (int kk = 0; kk < 16; ++kk) {
            float a[4], b[4];
            #pragma unroll
            for (int i2 = 0; i2 < 4; ++i2) a[i2] = As[kk][ty * 4 + i2];
            #pragma unroll
            for (int j2 = 0; j2 < 4; ++j2) b[j2] = Bs[kk][tx * 4 + j2];
            #pragma unroll
            for (int i2 = 0; i2 < 4; ++i2)
                #pragma unroll
                for (int j2 = 0; j2 < 4; ++j2) {
                    float df = a[i2] - b[j2];
                    acc[i2][j2] += df * df;
                }
        }
        __syncthreads();
    }
    #pragma unroll
    for (int i2 = 0; i2 < 4; ++i2)
        #pragma unroll
        for (int j2 = 0; j2 < 4; ++j2) {
            int r = bi * 64 + ty * 4 + i2;
            int c = bj * 64 + tx * 4 + j2;
            dist[r * B + c] = sqrtf(acc[i2][j2]);
        }
}

// ---------------- Kernel C: masked softmax per row (reference semantics) ----------------
__global__ __launch_bounds__(256) void k_softmax(
    const float* __restrict__ dist, const int* __restrict__ labels,
    float* __restrict__ W, float* __restrict__ rowS, float* __restrict__ rowCnt)
{
    int i = blockIdx.x, t = threadIdx.x;
    int li = labels[i];
    float d0 = dist[i * B + t];
    float d1 = dist[i * B + t + 256];
    int m0 = (labels[t] != li) && (d0 <= MARGIN);
    int m1 = (labels[t + 256] != li) && (d1 <= MARGIN);

    __shared__ float red[256];
    red[t] = fmaxf(m0 ? d0 : 0.f, m1 ? d1 : 0.f); __syncthreads();
    for (int s = 128; s > 0; s >>= 1) { if (t < s) red[t] = fmaxf(red[t], red[t + s]); __syncthreads(); }
    float maxd = red[0]; __syncthreads();

    float n0 = m0 ? expf(maxd - d0) : 0.f;
    float n1 = m1 ? expf(maxd - d1) : 0.f;
    red[t] = n0 + n1; __syncthreads();
    for (int s = 128; s > 0; s >>= 1) { if (t < s) red[t] += red[t + s]; __syncthreads(); }
    float Z = red[0] + 1e-6f; __syncthreads();
    float invZ = 1.f / Z;
    W[i * B + t]       = n0 * invZ;
    W[i * B + t + 256] = n1 * invZ;

    red[t] = (float)(m0 + m1); __syncthreads();
    for (int s = 128; s > 0; s >>= 1) { if (t < s) red[t] += red[t + s]; __syncthreads(); }
    if (t == 0) {
        rowS[i] = (Z - 1e-6f) * invZ;   // sum_j W_ij
        rowCnt[i] = red[0];
    }
}

// ---------------- Kernel F: finalize loss, global mask flag, last-write-wins winners ----------------
__global__ __launch_bounds__(512) void k_finalize(
    const float* __restrict__ rowLoss, const float* __restrict__ rowCnt,
    const int* __restrict__ labels, float* __restrict__ d_out0,
    float* __restrict__ flag, int* __restrict__ winner)
{
    int t = threadIdx.x; // 0..511
    __shared__ float red[512];
    __shared__ int labs[512];
    labs[t] = labels[t];
    red[t] = rowLoss[t]; __syncthreads();
    for (int s = 256; s > 0; s >>= 1) { if (t < s) red[t] += red[t + s]; __syncthreads(); }
    if (t == 0) *d_out0 = red[0] * (1.0f / (float)(B * D));
    __syncthreads();
    red[t] = rowCnt[t]; __syncthreads();
    for (int s = 256; s > 0; s >>= 1) { if (t < s) red[t] += red[t + s]; __syncthreads(); }
    if (t == 0) *flag = (red[0] < 1.0f) ? 0.f : 1.f;

    // winner[i] = 1 iff no later row has the same label (numpy scatter: last write wins)
    int li = labs[t];
    int w = 1;
    for (int j = t + 1; j < B; ++j) if (labs[j] == li) w = 0;
    winner[t] = w;
}

// ---------------- Kernel D: delta2 = S_i*cg_i - W·cg, fused epilogue + scatter ----------------
__global__ __launch_bounds__(256) void k_delta2_scatter(
    const float* __restrict__ W, const float* __restrict__ cg,
    const float* __restrict__ feat, const float* __restrict__ rowS,
    const int* __restrict__ labels, const int* __restrict__ winner,
    const float* __restrict__ flagp, float* __restrict__ outC)
{
    __shared__ float Ws[16][65];   // Ws[jj][i-in-tile]
    __shared__ float Cs[16][65];   // Cs[jj][d-in-tile]
    int tx = threadIdx.x, ty = threadIdx.y;
    int tid = ty * 16 + tx;
    int bi = blockIdx.y, bd = blockIdx.x;
    float acc[4][4] = {};
    for (int j0 = 0; j0 < B; j0 += 16) {
        #pragma unroll
        for (int it = 0; it < 4; ++it) {
            int idx = tid + it * 256;
            int r = idx >> 4, jj = idx & 15;
            Ws[jj][r] = W[(size_t)(bi * 64 + r) * B + j0 + jj];
            int dd = idx & 63, jj2 = idx >> 6;
            Cs[jj2][dd] = cg[(size_t)(j0 + jj2) * D + bd * 64 + dd];
        }
        __syncthreads();
        #pragma unroll
        for (int kk = 0; kk < 16; ++kk) {
            float w[4], c[4];
            #pragma unroll
            for (int i2 = 0; i2 < 4; ++i2) w[i2] = Ws[kk][ty * 4 + i2];
            #pragma unroll
            for (int j2 = 0; j2 < 4; ++j2) c[j2] = Cs[kk][tx * 4 + j2];
            #pragma unroll
            for (int i2 = 0; i2 < 4; ++i2)
                #pragma unroll
                for (int j2 = 0; j2 < 4; ++j2)
                    acc[i2][j2] += w[i2] * c[j2];
        }
        __syncthreads();
    }
    float flag = *flagp;
    #pragma unroll
    for (int i2 = 0; i2 < 4; ++i2) {
        int i = bi * 64 + ty * 4 + i2;
        float s = rowS[i];
        int wn = winner[i];
        size_t orow = (size_t)labels[i] * D;
        #pragma unroll
        for (int j2 = 0; j2 < 4; ++j2) {
            int d = bd * 64 + tx * 4 + j2;
            float c = cg[(size_t)i * D + d];
            float f = feat[(size_t)i * D + d];
            float delta2 = s * c - acc[i2][j2];
            float val = 0.5f * (c + f) - BETA * flag * delta2;
            if (wn) outC[orow + d] = val;
        }
    }
}

extern "C" void kernel_launch(void* const* d_in, const int* in_sizes, int n_in,
                              void* d_out, int out_size, void* d_ws, size_t ws_size,
                              hipStream_t stream)
{
    const float* features = (const float*)d_in[0];
    const int*   labels   = (const int*)d_in[1];
    const float* centers  = (const float*)d_in[2];

    float* out = (float*)d_out;            // out[0] = loss, out[1..] = new_centers
    float* outC = out + 1;

    // workspace layout (bytes)
    char* ws = (char*)d_ws;
    float* cg      = (float*)(ws);                     // 1 MB
    float* dist    = (float*)(ws + 1048576);           // 1 MB
    float* Wm      = (float*)(ws + 2097152);           // 1 MB
    float* rowLoss = (float*)(ws + 3145728);           // 2 KB
    float* rowS    = (float*)(ws + 3147776);           // 2 KB
    float* rowCnt  = (float*)(ws + 3149824);           // 2 KB
    float* flag    = (float*)(ws + 3151872);           // 4 B
    int*   winner  = (int*)  (ws + 3152896);           // 2 KB

    // Bulk copy centers -> new_centers with a fast custom kernel
    k_copy<<<2048, 256, 0, stream>>>((const f4*)centers, outC, NC * D / 4);

    k_gather_loss<<<B, 256, 0, stream>>>(centers, features, labels, cg, rowLoss);
    k_pairdist<<<dim3(8, 8), dim3(16, 16), 0, stream>>>(cg, dist);
    k_softmax<<<B, 256, 0, stream>>>(dist, labels, Wm, rowS, rowCnt);
    k_finalize<<<1, 512, 0, stream>>>(rowLoss, rowCnt, labels, out, flag, winner);
    k_delta2_scatter<<<dim3(8, 8), dim3(16, 16), 0, stream>>>(
        Wm, cg, features, rowS, labels, winner, flag, outC);
}